// Round 1
// baseline (609.522 us; speedup 1.0000x reference)
//
#include <hip/hip_runtime.h>
#include <hip/hip_bf16.h>
#include <stdint.h>

#define IN_F 4096
#define OUT_F 4096
#define NTOK 8192

typedef __attribute__((ext_vector_type(8))) __bf16 bf16x8;
typedef __attribute__((ext_vector_type(4))) float f32x4;

__device__ __forceinline__ unsigned short f2bf(float f) {
    unsigned u = __float_as_uint(f);
    u += 0x7fffu + ((u >> 16) & 1u);   // RNE; inputs are finite normals, no NaN care
    return (unsigned short)(u >> 16);
}

// --- scatter-add COO nonzeros into dense f32 W [OUT_F][IN_F] ---
__global__ void scatter_kernel(const float* __restrict__ vals,
                               const int* __restrict__ rows,
                               const int* __restrict__ cols,
                               float* __restrict__ W, int nnz) {
    int i = blockIdx.x * blockDim.x + threadIdx.x;
    if (i < nnz) {
        atomicAdd(&W[(size_t)rows[i] * IN_F + cols[i]], vals[i]);
    }
}

// --- f32 -> bf16 (RNE), vectorized float4 -> ushort4 ---
__global__ void cvt_kernel(const float4* __restrict__ in, ushort4* __restrict__ out, int n4) {
    int stride = gridDim.x * blockDim.x;
    for (int i = blockIdx.x * blockDim.x + threadIdx.x; i < n4; i += stride) {
        float4 v = in[i];
        ushort4 o;
        o.x = f2bf(v.x); o.y = f2bf(v.y); o.z = f2bf(v.z); o.w = f2bf(v.w);
        out[i] = o;
    }
}

// --- NT GEMM: C[M][N] = A[M][K] * B[N][K]^T + bias, bf16 in / f32 out ---
// m97 structure: 128x128 tile, BK=64, 4 waves (2x2), each wave 64x64 out via
// 4x4 grid of 16x16x32 bf16 MFMA. global_load_lds width-16 staging, 2-barrier loop.
#define GLD_LDS16(gp, lp)                                              \
    __builtin_amdgcn_global_load_lds(                                  \
        (__attribute__((address_space(1))) void*)(void*)(gp),          \
        (__attribute__((address_space(3))) void*)(lp), 16, 0, 0)

__global__ __launch_bounds__(256, 2)
void gemm_bt_bias(const ushort* __restrict__ A,   // x  bf16 [M][K]
                  const ushort* __restrict__ B,   // W  bf16 [N][K]
                  const float* __restrict__ bias, // [N]
                  float* __restrict__ C) {        // [M][N] f32
    constexpr int M = NTOK, N = OUT_F, K = IN_F;
    constexpr int TM = 128, TN = 128, BK = 64;

    __shared__ ushort As[TM * BK];   // 16 KB, row-major [row][k]
    __shared__ ushort Bs[TN * BK];   // 16 KB

    const int tid  = threadIdx.x;
    const int lane = tid & 63;
    const int wid  = tid >> 6;        // 0..3

    const int nbx  = N / TN;          // 32
    const int bx   = blockIdx.x % nbx;
    const int by   = blockIdx.x / nbx;
    const int brow = by * TM;
    const int bcol = bx * TN;

    const int wr = wid >> 1, wc = wid & 1;   // wave -> 64x64 subtile

    f32x4 acc[4][4] = {};

    // staging geometry: one global_load_lds per wave covers 8 rows x 64 cols
    // (lane -> row lane>>3, elems (lane&7)*8 .. +8); LDS dest is wave-uniform
    // base + lane*16B which matches linear [row][k] layout exactly.
    const int srow = wid * 8 + (lane >> 3);      // row within a 32-row group
    const int scol = (lane & 7) * 8;             // element col within BK
    const ushort* aptr = A + (size_t)(brow + srow) * K + scol;
    const ushort* bptr = B + (size_t)(bcol + srow) * K + scol;

    for (int k0 = 0; k0 < K; k0 += BK) {
        __syncthreads();   // prev iteration's ds_reads done before overwrite
#pragma unroll
        for (int r = 0; r < 4; ++r)
            GLD_LDS16(aptr + (size_t)(r * 32) * K + k0, &As[(r * 32 + wid * 8) * BK]);
#pragma unroll
        for (int r = 0; r < 4; ++r)
            GLD_LDS16(bptr + (size_t)(r * 32) * K + k0, &Bs[(r * 32 + wid * 8) * BK]);
        __syncthreads();   // compiler drains vmcnt before barrier -> tiles ready

#pragma unroll
        for (int kk = 0; kk < BK; kk += 32) {
            bf16x8 af[4], bg[4];
#pragma unroll
            for (int m = 0; m < 4; ++m)
                af[m] = *(const bf16x8*)&As[(wr * 64 + m * 16 + (lane & 15)) * BK + kk + (lane >> 4) * 8];
#pragma unroll
            for (int n = 0; n < 4; ++n)
                bg[n] = *(const bf16x8*)&Bs[(wc * 64 + n * 16 + (lane & 15)) * BK + kk + (lane >> 4) * 8];
#pragma unroll
            for (int m = 0; m < 4; ++m)
#pragma unroll
                for (int n = 0; n < 4; ++n)
                    acc[m][n] = __builtin_amdgcn_mfma_f32_16x16x32_bf16(af[m], bg[n], acc[m][n], 0, 0, 0);
        }
    }

    // epilogue: C/D layout col=lane&15, row=(lane>>4)*4+j  [m89-verified]
    const int crow0 = brow + wr * 64;
    const int ccol0 = bcol + wc * 64;
#pragma unroll
    for (int n = 0; n < 4; ++n) {
        const int col = ccol0 + n * 16 + (lane & 15);
        const float bv = bias[col];
#pragma unroll
        for (int m = 0; m < 4; ++m) {
            const int row0 = crow0 + m * 16 + (lane >> 4) * 4;
#pragma unroll
            for (int j = 0; j < 4; ++j)
                C[(size_t)(row0 + j) * N + col] = acc[m][n][j] + bv;
        }
    }
}

extern "C" void kernel_launch(void* const* d_in, const int* in_sizes, int n_in,
                              void* d_out, int out_size, void* d_ws, size_t ws_size,
                              hipStream_t stream) {
    const float* x    = (const float*)d_in[0];   // [8192][4096] f32
    const float* vals = (const float*)d_in[1];   // [NNZ]
    const int*   rows = (const int*)d_in[2];     // [NNZ]
    const int*   cols = (const int*)d_in[3];     // [NNZ]
    const float* bias = (const float*)d_in[4];   // [4096]
    float* out = (float*)d_out;                  // [8192][4096] f32
    const int nnz = in_sizes[1];

    char* ws = (char*)d_ws;
    float*  Wf = (float*)ws;                                  // 64 MB f32 W
    ushort* Wb = (ushort*)(ws + (size_t)64 * 1024 * 1024);    // 32 MB bf16 W
    ushort* Xb = (ushort*)(ws + (size_t)96 * 1024 * 1024);    // 64 MB bf16 x

    // 1) zero W accumulator (ws is poisoned 0xAA each call)
    hipMemsetAsync(Wf, 0, (size_t)OUT_F * IN_F * sizeof(float), stream);
    // 2) scatter-add nonzeros (duplicates sum in f32, matching reference)
    scatter_kernel<<<(nnz + 255) / 256, 256, 0, stream>>>(vals, rows, cols, Wf, nnz);
    // 3) convert W and x to bf16
    cvt_kernel<<<2048, 256, 0, stream>>>((const float4*)Wf, (ushort4*)Wb, OUT_F * IN_F / 4);
    cvt_kernel<<<2048, 256, 0, stream>>>((const float4*)x,  (ushort4*)Xb, NTOK * IN_F / 4);
    // 4) bf16 MFMA GEMM with fused bias
    gemm_bt_bias<<<dim3((NTOK / 128) * (OUT_F / 128)), 256, 0, stream>>>(Xb, Wb, bias, out);
}

// Round 3
// 551.536 us; speedup vs baseline: 1.1051x; 1.1051x over previous
//
#include <hip/hip_runtime.h>
#include <hip/hip_bf16.h>
#include <stdint.h>

#define IN_F 4096
#define OUT_F 4096
#define NTOK 8192

typedef __attribute__((ext_vector_type(8))) __bf16 bf16x8;
typedef __attribute__((ext_vector_type(4))) float f32x4;

__device__ __forceinline__ unsigned short f2bf(float f) {
    unsigned u = __float_as_uint(f);
    u += 0x7fffu + ((u >> 16) & 1u);   // RNE
    return (unsigned short)(u >> 16);
}

// --- scatter-add COO nonzeros into dense f32 W [OUT_F][IN_F] ---
__global__ void scatter_kernel(const float* __restrict__ vals,
                               const int* __restrict__ rows,
                               const int* __restrict__ cols,
                               float* __restrict__ W, int nnz) {
    int i = blockIdx.x * blockDim.x + threadIdx.x;
    if (i < nnz) atomicAdd(&W[(size_t)rows[i] * IN_F + cols[i]], vals[i]);
}

// --- fused f32->bf16 for W and x in one launch ---
__global__ void cvt2_kernel(const float4* __restrict__ a, ushort4* __restrict__ oa, int na4,
                            const float4* __restrict__ b, ushort4* __restrict__ ob, int nb4) {
    int stride = gridDim.x * blockDim.x;
    int tot = na4 + nb4;
    for (int i = blockIdx.x * blockDim.x + threadIdx.x; i < tot; i += stride) {
        const float4* src; ushort4* dst; int j;
        if (i < na4) { src = a; dst = oa; j = i; }
        else         { src = b; dst = ob; j = i - na4; }
        float4 v = src[j];
        ushort4 o;
        o.x = f2bf(v.x); o.y = f2bf(v.y); o.z = f2bf(v.z); o.w = f2bf(v.w);
        dst[j] = o;
    }
}

// ---------------------------------------------------------------------------
// NT GEMM: C[M][N] = A[M][K] * B[N][K]^T + bias, bf16 in / f32 out.
// 256x256 tile, 8 waves (2Mx4N), BK=32, 4-deep LDS pipeline with counted
// vmcnt(8) (never drained to 0 in steady state), raw s_barrier, setprio
// around the MFMA cluster, and a conflict-free XOR swizzle
// (lin ^= ((lin>>6)&7)<<3) applied as pre-swizzled global source +
// swizzled ds_read (gload_lds dest stays linear).
// ---------------------------------------------------------------------------
#define GLD_LDS16(gp, lp)                                              \
    __builtin_amdgcn_global_load_lds(                                  \
        (__attribute__((address_space(1))) void*)(void*)(gp),          \
        (__attribute__((address_space(3))) void*)(lp), 16, 0, 0)

// per-thread: 4 loads per K-tile (A rounds 0/1, B rounds 0/1)
#define STAGE(tt) do {                                                 \
    const int _b = ((tt) & 3) * 16384;                                 \
    const size_t _k = (size_t)(tt) * 32;                               \
    GLD_LDS16(A0 + _k, &lds[_b + ldst0]);                              \
    GLD_LDS16(A1 + _k, &lds[_b + ldst1]);                              \
    GLD_LDS16(B0 + _k, &lds[_b + 8192 + ldst0]);                       \
    GLD_LDS16(B1 + _k, &lds[_b + 8192 + ldst1]);                       \
} while (0)

template<int VM>
__device__ __forceinline__ void kiter(int t,
        const ushort* __restrict__ A0, const ushort* __restrict__ A1,
        const ushort* __restrict__ B0, const ushort* __restrict__ B1,
        ushort* lds, int ldst0, int ldst1,
        const int (&aoff)[8], const int (&boff)[4], f32x4 (&acc)[8][4]) {
    if constexpr (VM == 8)      asm volatile("s_waitcnt vmcnt(8)" ::: "memory");
    else if constexpr (VM == 4) asm volatile("s_waitcnt vmcnt(4)" ::: "memory");
    else                        asm volatile("s_waitcnt vmcnt(0)" ::: "memory");
    __builtin_amdgcn_s_barrier();          // tile t fully landed for all threads
    if (t + 3 < IN_F / 32) STAGE(t + 3);   // prefetch: buf[(t+3)&3] == buf[(t-1)&3],
                                           // whose tile-(t-1) reads completed before
                                           // this barrier -> issue-order safe
    const int bb = (t & 3) * 16384;
    bf16x8 af[8], bg[4];
#pragma unroll
    for (int m = 0; m < 8; ++m) af[m] = *(const bf16x8*)&lds[bb + aoff[m]];
#pragma unroll
    for (int n = 0; n < 4; ++n) bg[n] = *(const bf16x8*)&lds[bb + 8192 + boff[n]];
    __builtin_amdgcn_s_setprio(1);
#pragma unroll
    for (int m = 0; m < 8; ++m)
#pragma unroll
        for (int n = 0; n < 4; ++n)
            acc[m][n] = __builtin_amdgcn_mfma_f32_16x16x32_bf16(af[m], bg[n], acc[m][n], 0, 0, 0);
    __builtin_amdgcn_s_setprio(0);
}

__global__ __launch_bounds__(512, 2)
void gemm_bt_bias(const ushort* __restrict__ A,   // x  bf16 [M][K]
                  const ushort* __restrict__ B,   // W  bf16 [N][K]
                  const float* __restrict__ bias,
                  float* __restrict__ C) {        // [M][N] f32
    constexpr int N = OUT_F, K = IN_F;
    constexpr int NT = K / 32;                    // 128 K-tiles

    extern __shared__ ushort lds[];               // 128 KB: 4 bufs x (A 8K + B 8K elems)

    const int tid  = threadIdx.x;
    const int lane = tid & 63;
    const int wid  = tid >> 6;

    // XCD-contiguous block swizzle (512 blocks, 8 XCDs, 64 per XCD)
    const int bid = blockIdx.x;
    const int nb  = (bid & 7) * 64 + (bid >> 3);
    const int by = nb >> 4, bx = nb & 15;         // 32 M-tiles x 16 N-tiles
    const int brow = by * 256, bcol = bx * 256;

    const int wr = wid >> 2, wc = wid & 3;        // wave -> 128x64 output

    // staging: linear LDS dest elem d -> global element swz(d)
    const int d0 = tid * 8, d1 = (512 + tid) * 8;
    const int s0 = d0 ^ (((d0 >> 6) & 7) << 3);
    const int s1 = d1 ^ (((d1 >> 6) & 7) << 3);
    const ushort* A0 = A + (size_t)(brow + (s0 >> 5)) * K + (s0 & 31);
    const ushort* A1 = A + (size_t)(brow + (s1 >> 5)) * K + (s1 & 31);
    const ushort* B0 = B + (size_t)(bcol + (s0 >> 5)) * K + (s0 & 31);
    const ushort* B1 = B + (size_t)(bcol + (s1 >> 5)) * K + (s1 & 31);
    const int ldst0 = (wid * 64) * 8;             // wave-uniform LDS bases (+lane*16B by HW)
    const int ldst1 = (512 + wid * 64) * 8;

    // swizzled fragment offsets ([256][32] tile viewed as [128][64] vrows)
    const int fr = lane & 15, kq = (lane >> 4) * 8;
    int aoff[8], boff[4];
#pragma unroll
    for (int m = 0; m < 8; ++m) {
        int lin = (wr * 128 + m * 16 + fr) * 32 + kq;
        aoff[m] = lin ^ (((lin >> 6) & 7) << 3);
    }
#pragma unroll
    for (int n = 0; n < 4; ++n) {
        int lin = (wc * 64 + n * 16 + fr) * 32 + kq;
        boff[n] = lin ^ (((lin >> 6) & 7) << 3);
    }

    f32x4 acc[8][4] = {};

    STAGE(0); STAGE(1); STAGE(2);                 // fill pipeline (12 loads in flight)

    for (int t = 0; t < NT - 2; ++t)
        kiter<8>(t, A0, A1, B0, B1, lds, ldst0, ldst1, aoff, boff, acc);
    kiter<4>(NT - 2, A0, A1, B0, B1, lds, ldst0, ldst1, aoff, boff, acc);
    kiter<0>(NT - 1, A0, A1, B0, B1, lds, ldst0, ldst1, aoff, boff, acc);

    // epilogue: C/D layout col=lane&15, row=(lane>>4)*4+j  [m89]
    const int crow0 = brow + wr * 128;
    const int ccol0 = bcol + wc * 64;
#pragma unroll
    for (int n = 0; n < 4; ++n) {
        const int col = ccol0 + n * 16 + fr;
        const float bv = bias[col];
#pragma unroll
        for (int m = 0; m < 8; ++m) {
            const int r0 = crow0 + m * 16 + (lane >> 4) * 4;
#pragma unroll
            for (int j = 0; j < 4; ++j)
                C[(size_t)(r0 + j) * N + col] = acc[m][n][j] + bv;
        }
    }
}

extern "C" void kernel_launch(void* const* d_in, const int* in_sizes, int n_in,
                              void* d_out, int out_size, void* d_ws, size_t ws_size,
                              hipStream_t stream) {
    const float* x    = (const float*)d_in[0];
    const float* vals = (const float*)d_in[1];
    const int*   rows = (const int*)d_in[2];
    const int*   cols = (const int*)d_in[3];
    const float* bias = (const float*)d_in[4];
    float* out = (float*)d_out;
    const int nnz = in_sizes[1];

    char* ws = (char*)d_ws;
    float*  Wf = (float*)ws;                                  // 64 MB f32 W
    ushort* Wb = (ushort*)(ws + (size_t)64 * 1024 * 1024);    // 32 MB bf16 W
    ushort* Xb = (ushort*)(ws + (size_t)96 * 1024 * 1024);    // 64 MB bf16 x

    hipMemsetAsync(Wf, 0, (size_t)OUT_F * IN_F * sizeof(float), stream);
    scatter_kernel<<<(nnz + 255) / 256, 256, 0, stream>>>(vals, rows, cols, Wf, nnz);
    cvt2_kernel<<<4096, 256, 0, stream>>>((const float4*)Wf, (ushort4*)Wb, OUT_F * IN_F / 4,
                                          (const float4*)x,  (ushort4*)Xb, NTOK * IN_F / 4);
    gemm_bt_bias<<<dim3((NTOK / 256) * (OUT_F / 256)), 512, 131072, stream>>>(Xb, Wb, bias, out);
}